// Round 1
// baseline (1009.201 us; speedup 1.0000x reference)
//
#include <hip/hip_runtime.h>
#include <math.h>

#define DMODEL 256
#define NHEAD 8
#define NLVL 3
#define NPTS 4
#define HDIM 32
#define QLEN 10000
#define BATCH 4

// ---------------------------------------------------------------------------
// K1: value projection.  v[b][pos][c] = sum_k feat[b][k][pos] * Wv[k][c] + bv[c]
// feat is [B,256,HW] (channel-major) so A-tile staging is naturally coalesced.
// Tile: 64 positions x 256 cols, 256 threads, acc[8][8] per thread.
// ---------------------------------------------------------------------------
__global__ __launch_bounds__(256) void vproj_kernel(
    const float* __restrict__ feat, const float* __restrict__ Wv,
    const float* __restrict__ bv, float* __restrict__ vout, int HW)
{
    __shared__ float As[16 * 64];    // [kk][pos]
    __shared__ float Ws[16 * 256];   // [kk][col]

    const int b    = blockIdx.y;
    const int pos0 = blockIdx.x * 64;
    const int tid  = threadIdx.x;
    const int tp   = tid >> 5;   // 0..7 : position group (8 positions each)
    const int tc   = tid & 31;   // 0..31: column lane (cols tc + 32*j)

    float acc[8][8];
#pragma unroll
    for (int i = 0; i < 8; ++i)
#pragma unroll
        for (int j = 0; j < 8; ++j) acc[i][j] = 0.f;

    const float* fb = feat + (size_t)b * DMODEL * HW;

    for (int k0 = 0; k0 < 256; k0 += 16) {
        // stage A chunk [16][64] (transposed feat is already k-major: coalesced)
#pragma unroll
        for (int it = 0; it < 4; ++it) {
            const int kk = (tid >> 6) + it * 4;
            const int p  = tid & 63;
            float va = 0.f;
            if (pos0 + p < HW) va = fb[(size_t)(k0 + kk) * HW + pos0 + p];
            As[kk * 64 + p] = va;
        }
        // stage W chunk [16][256]
#pragma unroll
        for (int kk = 0; kk < 16; ++kk)
            Ws[kk * 256 + tid] = Wv[(size_t)(k0 + kk) * 256 + tid];
        __syncthreads();

#pragma unroll
        for (int kk = 0; kk < 16; ++kk) {
            const float4 a0 = *(const float4*)&As[kk * 64 + tp * 8];
            const float4 a1 = *(const float4*)&As[kk * 64 + tp * 8 + 4];
            const float a[8] = {a0.x, a0.y, a0.z, a0.w, a1.x, a1.y, a1.z, a1.w};
            float w[8];
#pragma unroll
            for (int j = 0; j < 8; ++j) w[j] = Ws[kk * 256 + tc + 32 * j];
#pragma unroll
            for (int i = 0; i < 8; ++i)
#pragma unroll
                for (int j = 0; j < 8; ++j)
                    acc[i][j] = fmaf(a[i], w[j], acc[i][j]);
        }
        __syncthreads();
    }

    float bb[8];
#pragma unroll
    for (int j = 0; j < 8; ++j) bb[j] = bv[tc + 32 * j];

    float* vb = vout + (size_t)b * HW * 256;
#pragma unroll
    for (int i = 0; i < 8; ++i) {
        const int p = pos0 + tp * 8 + i;
        if (p < HW) {
#pragma unroll
            for (int j = 0; j < 8; ++j)
                vb[(size_t)p * 256 + tc + 32 * j] = acc[i][j] + bb[j];
        }
    }
}

// ---------------------------------------------------------------------------
// K2: fused query-side GEMM (logits[32][288]) + tanh/softmax epilogue +
//     bilinear sampling + attention-weighted accumulation.
// Block: 256 threads, 32 query rows.  After the GEMM, logits go to LDS and
// each thread owns one (q,h) pair: 24 offset logits + 12 attn logits.
// ---------------------------------------------------------------------------
__global__ __launch_bounds__(256) void qsamp_kernel(
    const float* __restrict__ query, const float* __restrict__ ref,
    const float* __restrict__ Woff, const float* __restrict__ boff,
    const float* __restrict__ Wattn, const float* __restrict__ battn,
    const float* __restrict__ v0, const float* __restrict__ v1,
    const float* __restrict__ v2, float* __restrict__ outp)
{
    __shared__ float Qs[16 * 36];      // [kk][r], stride 36 (16B-alignable, 2-way max)
    __shared__ float SH[32 * 288];     // GEMM W-tile (first 16*288) then logits[32][288]
    float* WL = SH;
    float* LG = SH;

    const int row0 = blockIdx.x * 32;
    const int tid  = threadIdx.x;
    const int tp   = tid >> 5;   // 0..7 -> rows tp*4+i
    const int tc   = tid & 31;   // cols tc + 32*j, j<9

    float acc[4][9];
#pragma unroll
    for (int i = 0; i < 4; ++i)
#pragma unroll
        for (int j = 0; j < 9; ++j) acc[i][j] = 0.f;

    for (int k0 = 0; k0 < 256; k0 += 16) {
        // stage Q chunk transposed: [kk][r]
        if (tid < 128) {
            const int r  = tid >> 2;
            const int kq = (tid & 3) * 4;
            const float4 qv =
                *(const float4*)&query[(size_t)(row0 + r) * 256 + k0 + kq];
            Qs[(kq + 0) * 36 + r] = qv.x;
            Qs[(kq + 1) * 36 + r] = qv.y;
            Qs[(kq + 2) * 36 + r] = qv.z;
            Qs[(kq + 3) * 36 + r] = qv.w;
        }
        // stage W chunk [16][288]: cols 0..191 = W_off, 192..287 = W_attn
#pragma unroll
        for (int kk = 0; kk < 16; ++kk) {
            for (int n = tid; n < 288; n += 256) {
                const float wv = (n < 192)
                    ? Woff[(size_t)(k0 + kk) * 192 + n]
                    : Wattn[(size_t)(k0 + kk) * 96 + (n - 192)];
                WL[kk * 288 + n] = wv;
            }
        }
        __syncthreads();

#pragma unroll
        for (int kk = 0; kk < 16; ++kk) {
            const float4 av = *(const float4*)&Qs[kk * 36 + tp * 4];
            const float a[4] = {av.x, av.y, av.z, av.w};
            float w[9];
#pragma unroll
            for (int j = 0; j < 9; ++j) w[j] = WL[kk * 288 + tc + 32 * j];
#pragma unroll
            for (int i = 0; i < 4; ++i)
#pragma unroll
                for (int j = 0; j < 9; ++j)
                    acc[i][j] = fmaf(a[i], w[j], acc[i][j]);
        }
        __syncthreads();
    }

    // write logits (+bias) to LDS
#pragma unroll
    for (int j = 0; j < 9; ++j) {
        const int col = tc + 32 * j;
        const float bias = (col < 192) ? boff[col] : battn[col - 192];
#pragma unroll
        for (int i = 0; i < 4; ++i)
            LG[(tp * 4 + i) * 288 + col] = acc[i][j] + bias;
    }
    __syncthreads();

    // ------------- sampling: one thread per (q,h) -------------
    const int qs  = tid >> 3;
    const int h   = tid & 7;
    const int row = row0 + qs;
    const int b   = row / QLEN;
    const float* lg = &LG[qs * 288];

    // softmax over 12 attn logits
    float al[12];
#pragma unroll
    for (int j = 0; j < 12; ++j) al[j] = lg[192 + h * 12 + j];
    float m = al[0];
#pragma unroll
    for (int j = 1; j < 12; ++j) m = fmaxf(m, al[j]);
    float s = 0.f;
#pragma unroll
    for (int j = 0; j < 12; ++j) { al[j] = expf(al[j] - m); s += al[j]; }
    const float inv = 1.f / s;

    const float refx = ref[(size_t)row * 2 + 0];
    const float refy = ref[(size_t)row * 2 + 1];

    float oacc[32];
#pragma unroll
    for (int u = 0; u < 32; ++u) oacc[u] = 0.f;

#pragma unroll
    for (int l = 0; l < 3; ++l) {
        const int Wl = (l == 0) ? 100 : (l == 1) ? 50 : 25;
        const int Hl = Wl;
        const float* vb =
            (l == 0) ? v0 + (size_t)b * 10000 * 256 :
            (l == 1) ? v1 + (size_t)b * 2500  * 256 :
                       v2 + (size_t)b * 625   * 256;
#pragma unroll
        for (int p = 0; p < 4; ++p) {
            const float ox = 0.5f * tanhf(lg[h * 24 + l * 8 + p * 2 + 0]);
            const float oy = 0.5f * tanhf(lg[h * 24 + l * 8 + p * 2 + 1]);
            const float x = (refx + ox) * (float)Wl - 0.5f;
            const float y = (refy + oy) * (float)Hl - 0.5f;
            const float xf = floorf(x), yf = floorf(y);
            const int   x0i = (int)xf, y0i = (int)yf;
            const float wx = x - xf, wy = y - yf;
            const float aw = al[l * 4 + p] * inv;
#pragma unroll
            for (int cy = 0; cy < 2; ++cy) {
#pragma unroll
                for (int cx = 0; cx < 2; ++cx) {
                    const int xi = x0i + cx, yi = y0i + cy;
                    if (xi < 0 || xi >= Wl || yi < 0 || yi >= Hl) continue;
                    const float cw = aw * (cx ? wx : 1.f - wx)
                                        * (cy ? wy : 1.f - wy);
                    const float4* cp = (const float4*)(vb +
                        ((size_t)(yi * Wl + xi) * 256 + h * 32));
#pragma unroll
                    for (int u = 0; u < 8; ++u) {
                        const float4 vv = cp[u];
                        oacc[4 * u + 0] = fmaf(cw, vv.x, oacc[4 * u + 0]);
                        oacc[4 * u + 1] = fmaf(cw, vv.y, oacc[4 * u + 1]);
                        oacc[4 * u + 2] = fmaf(cw, vv.z, oacc[4 * u + 2]);
                        oacc[4 * u + 3] = fmaf(cw, vv.w, oacc[4 * u + 3]);
                    }
                }
            }
        }
    }

    float4* op = (float4*)(outp + (size_t)row * 256 + h * 32);
#pragma unroll
    for (int u = 0; u < 8; ++u)
        op[u] = make_float4(oacc[4 * u + 0], oacc[4 * u + 1],
                            oacc[4 * u + 2], oacc[4 * u + 3]);
}

// ---------------------------------------------------------------------------
// K3: output projection.  out[r][n] = sum_k A[r][k] * Wo[k][n] + bo[n]
// Tile: 64 rows x 256 cols, 256 threads, acc[8][8].
// A staged transposed into LDS (stride 68: 16B-aligned rows, <=2-way banks).
// ---------------------------------------------------------------------------
__global__ __launch_bounds__(256) void outproj_kernel(
    const float* __restrict__ A, const float* __restrict__ Wo,
    const float* __restrict__ bo, float* __restrict__ out)
{
    __shared__ float As[16 * 68];    // [kk][r]
    __shared__ float Ws[16 * 256];

    const int row0 = blockIdx.x * 64;
    const int tid  = threadIdx.x;
    const int tp   = tid >> 5;
    const int tc   = tid & 31;

    float acc[8][8];
#pragma unroll
    for (int i = 0; i < 8; ++i)
#pragma unroll
        for (int j = 0; j < 8; ++j) acc[i][j] = 0.f;

    for (int k0 = 0; k0 < 256; k0 += 16) {
        {
            const int r  = tid >> 2;
            const int kq = (tid & 3) * 4;
            const float4 av =
                *(const float4*)&A[(size_t)(row0 + r) * 256 + k0 + kq];
            As[(kq + 0) * 68 + r] = av.x;
            As[(kq + 1) * 68 + r] = av.y;
            As[(kq + 2) * 68 + r] = av.z;
            As[(kq + 3) * 68 + r] = av.w;
        }
#pragma unroll
        for (int kk = 0; kk < 16; ++kk)
            Ws[kk * 256 + tid] = Wo[(size_t)(k0 + kk) * 256 + tid];
        __syncthreads();

#pragma unroll
        for (int kk = 0; kk < 16; ++kk) {
            const float4 a0 = *(const float4*)&As[kk * 68 + tp * 8];
            const float4 a1 = *(const float4*)&As[kk * 68 + tp * 8 + 4];
            const float a[8] = {a0.x, a0.y, a0.z, a0.w, a1.x, a1.y, a1.z, a1.w};
            float w[8];
#pragma unroll
            for (int j = 0; j < 8; ++j) w[j] = Ws[kk * 256 + tc + 32 * j];
#pragma unroll
            for (int i = 0; i < 8; ++i)
#pragma unroll
                for (int j = 0; j < 8; ++j)
                    acc[i][j] = fmaf(a[i], w[j], acc[i][j]);
        }
        __syncthreads();
    }

    float bb[8];
#pragma unroll
    for (int j = 0; j < 8; ++j) bb[j] = bo[tc + 32 * j];

#pragma unroll
    for (int i = 0; i < 8; ++i) {
        const int r = row0 + tp * 8 + i;
#pragma unroll
        for (int j = 0; j < 8; ++j)
            out[(size_t)r * 256 + tc + 32 * j] = acc[i][j] + bb[j];
    }
}

// ---------------------------------------------------------------------------
extern "C" void kernel_launch(void* const* d_in, const int* in_sizes, int n_in,
                              void* d_out, int out_size, void* d_ws, size_t ws_size,
                              hipStream_t stream)
{
    const float* query  = (const float*)d_in[0];
    const float* value0 = (const float*)d_in[1];
    const float* value1 = (const float*)d_in[2];
    const float* value2 = (const float*)d_in[3];
    const float* refpts = (const float*)d_in[4];
    const float* Woff   = (const float*)d_in[5];
    const float* boff   = (const float*)d_in[6];
    const float* Wattn  = (const float*)d_in[7];
    const float* battn  = (const float*)d_in[8];
    const float* Wval   = (const float*)d_in[9];
    const float* bval   = (const float*)d_in[10];
    const float* Wout   = (const float*)d_in[11];
    const float* bout   = (const float*)d_in[12];
    float* out = (float*)d_out;

    float* ws = (float*)d_ws;
    float* v0   = ws;                                        // 4*10000*256
    float* v1   = v0 + (size_t)BATCH * 10000 * 256;          // 4*2500*256
    float* v2   = v1 + (size_t)BATCH * 2500  * 256;          // 4*625*256
    float* outp = v2 + (size_t)BATCH * 625   * 256;          // 40000*256

    vproj_kernel<<<dim3(157, BATCH), 256, 0, stream>>>(value0, Wval, bval, v0, 10000);
    vproj_kernel<<<dim3(40,  BATCH), 256, 0, stream>>>(value1, Wval, bval, v1, 2500);
    vproj_kernel<<<dim3(10,  BATCH), 256, 0, stream>>>(value2, Wval, bval, v2, 625);

    qsamp_kernel<<<1250, 256, 0, stream>>>(query, refpts, Woff, boff,
                                           Wattn, battn, v0, v1, v2, outp);

    outproj_kernel<<<625, 256, 0, stream>>>(outp, Wout, bout, out);
}

// Round 2
// 934.981 us; speedup vs baseline: 1.0794x; 1.0794x over previous
//
#include <hip/hip_runtime.h>
#include <math.h>

#define DMODEL 256
#define NHEAD 8
#define NLVL 3
#define NPTS 4
#define HDIM 32
#define QLEN 10000
#define BATCH 4

__device__ __forceinline__ float tanh_fast(float x)
{
    const float ax = fabsf(x);
    const float e  = __expf(-2.f * ax);
    const float t  = (1.f - e) / (1.f + e);
    return copysignf(t, x);
}

// ---------------------------------------------------------------------------
// K1: value projection.  v[b][pos][c] = sum_k feat[b][k][pos] * Wv[k][c] + bv[c]
// ---------------------------------------------------------------------------
__global__ __launch_bounds__(256) void vproj_kernel(
    const float* __restrict__ feat, const float* __restrict__ Wv,
    const float* __restrict__ bv, float* __restrict__ vout, int HW)
{
    __shared__ float As[16 * 64];    // [kk][pos]
    __shared__ float Ws[16 * 256];   // [kk][col]

    const int b    = blockIdx.y;
    const int pos0 = blockIdx.x * 64;
    const int tid  = threadIdx.x;
    const int tp   = tid >> 5;
    const int tc   = tid & 31;

    float acc[8][8];
#pragma unroll
    for (int i = 0; i < 8; ++i)
#pragma unroll
        for (int j = 0; j < 8; ++j) acc[i][j] = 0.f;

    const float* fb = feat + (size_t)b * DMODEL * HW;

    for (int k0 = 0; k0 < 256; k0 += 16) {
#pragma unroll
        for (int it = 0; it < 4; ++it) {
            const int kk = (tid >> 6) + it * 4;
            const int p  = tid & 63;
            float va = 0.f;
            if (pos0 + p < HW) va = fb[(size_t)(k0 + kk) * HW + pos0 + p];
            As[kk * 64 + p] = va;
        }
#pragma unroll
        for (int kk = 0; kk < 16; ++kk)
            Ws[kk * 256 + tid] = Wv[(size_t)(k0 + kk) * 256 + tid];
        __syncthreads();

#pragma unroll
        for (int kk = 0; kk < 16; ++kk) {
            const float4 a0 = *(const float4*)&As[kk * 64 + tp * 8];
            const float4 a1 = *(const float4*)&As[kk * 64 + tp * 8 + 4];
            const float a[8] = {a0.x, a0.y, a0.z, a0.w, a1.x, a1.y, a1.z, a1.w};
            float w[8];
#pragma unroll
            for (int j = 0; j < 8; ++j) w[j] = Ws[kk * 256 + tc + 32 * j];
#pragma unroll
            for (int i = 0; i < 8; ++i)
#pragma unroll
                for (int j = 0; j < 8; ++j)
                    acc[i][j] = fmaf(a[i], w[j], acc[i][j]);
        }
        __syncthreads();
    }

    float bb[8];
#pragma unroll
    for (int j = 0; j < 8; ++j) bb[j] = bv[tc + 32 * j];

    float* vb = vout + (size_t)b * HW * 256;
#pragma unroll
    for (int i = 0; i < 8; ++i) {
        const int p = pos0 + tp * 8 + i;
        if (p < HW) {
#pragma unroll
            for (int j = 0; j < 8; ++j)
                vb[(size_t)p * 256 + tc + 32 * j] = acc[i][j] + bb[j];
        }
    }
}

// ---------------------------------------------------------------------------
// K2: fused query-side GEMM (logits[32][288]) + tanh/softmax + bilinear
//     sampling.  Sampling decomposition: ONE WAVE = ONE QUERY.
//     lane = quad(0..7) + 8*h  ->  per-(corner) wave-load is 8 coalesced
//     128B segments (per-lane offset = idx(h)*256 + lane*4).
// ---------------------------------------------------------------------------
__global__ __launch_bounds__(256) void qsamp_kernel(
    const float* __restrict__ query, const float* __restrict__ ref,
    const float* __restrict__ Woff, const float* __restrict__ boff,
    const float* __restrict__ Wattn, const float* __restrict__ battn,
    const float* __restrict__ v0, const float* __restrict__ v1,
    const float* __restrict__ v2, float* __restrict__ outp)
{
    __shared__ float Qs[16 * 36];      // [kk][r]
    __shared__ float SH[32 * 288];     // W-tile during GEMM, then logits[32][288]
    float* WL = SH;
    float* LG = SH;

    const int row0 = blockIdx.x * 32;
    const int tid  = threadIdx.x;
    const int tp   = tid >> 5;
    const int tc   = tid & 31;

    float acc[4][9];
#pragma unroll
    for (int i = 0; i < 4; ++i)
#pragma unroll
        for (int j = 0; j < 9; ++j) acc[i][j] = 0.f;

    for (int k0 = 0; k0 < 256; k0 += 16) {
        if (tid < 128) {
            const int r  = tid >> 2;
            const int kq = (tid & 3) * 4;
            const float4 qv =
                *(const float4*)&query[(size_t)(row0 + r) * 256 + k0 + kq];
            Qs[(kq + 0) * 36 + r] = qv.x;
            Qs[(kq + 1) * 36 + r] = qv.y;
            Qs[(kq + 2) * 36 + r] = qv.z;
            Qs[(kq + 3) * 36 + r] = qv.w;
        }
#pragma unroll
        for (int kk = 0; kk < 16; ++kk) {
            for (int n = tid; n < 288; n += 256) {
                const float wv = (n < 192)
                    ? Woff[(size_t)(k0 + kk) * 192 + n]
                    : Wattn[(size_t)(k0 + kk) * 96 + (n - 192)];
                WL[kk * 288 + n] = wv;
            }
        }
        __syncthreads();

#pragma unroll
        for (int kk = 0; kk < 16; ++kk) {
            const float4 av = *(const float4*)&Qs[kk * 36 + tp * 4];
            const float a[4] = {av.x, av.y, av.z, av.w};
            float w[9];
#pragma unroll
            for (int j = 0; j < 9; ++j) w[j] = WL[kk * 288 + tc + 32 * j];
#pragma unroll
            for (int i = 0; i < 4; ++i)
#pragma unroll
                for (int j = 0; j < 9; ++j)
                    acc[i][j] = fmaf(a[i], w[j], acc[i][j]);
        }
        __syncthreads();
    }

#pragma unroll
    for (int j = 0; j < 9; ++j) {
        const int col = tc + 32 * j;
        const float bias = (col < 192) ? boff[col] : battn[col - 192];
#pragma unroll
        for (int i = 0; i < 4; ++i)
            LG[(tp * 4 + i) * 288 + col] = acc[i][j] + bias;
    }
    __syncthreads();

    // ------------- sampling: one wave per query -------------
    const int lane = tid & 63;
    const int wv   = tid >> 6;          // wave id 0..3
    const int h    = lane >> 3;         // head 0..7

#pragma unroll 1
    for (int i = 0; i < 8; ++i) {
        const int qs  = wv * 8 + i;
        const int row = row0 + qs;
        const int b   = row / QLEN;
        const float* lg = &LG[qs * 288];

        // softmax over 12 attn logits (replicated across the 8 lanes of h)
        float al[12];
#pragma unroll
        for (int j = 0; j < 12; ++j) al[j] = lg[192 + h * 12 + j];
        float m = al[0];
#pragma unroll
        for (int j = 1; j < 12; ++j) m = fmaxf(m, al[j]);
        float s = 0.f;
#pragma unroll
        for (int j = 0; j < 12; ++j) { al[j] = __expf(al[j] - m); s += al[j]; }
        const float inv = 1.f / s;

        const float refx = ref[(size_t)row * 2 + 0];
        const float refy = ref[(size_t)row * 2 + 1];

        float o0 = 0.f, o1 = 0.f, o2 = 0.f, o3 = 0.f;

#pragma unroll
        for (int l = 0; l < 3; ++l) {
            const int Wl = (l == 0) ? 100 : (l == 1) ? 50 : 25;
            const int Hl = Wl;
            const float* vb =
                (l == 0) ? v0 + (size_t)b * 10000 * 256 :
                (l == 1) ? v1 + (size_t)b * 2500  * 256 :
                           v2 + (size_t)b * 625   * 256;

            int   cidx[16];
            float cwt[16];
#pragma unroll
            for (int p = 0; p < 4; ++p) {
                const float ox = 0.5f * tanh_fast(lg[h * 24 + l * 8 + p * 2 + 0]);
                const float oy = 0.5f * tanh_fast(lg[h * 24 + l * 8 + p * 2 + 1]);
                const float x = (refx + ox) * (float)Wl - 0.5f;
                const float y = (refy + oy) * (float)Hl - 0.5f;
                const float xf = floorf(x), yf = floorf(y);
                const int   x0i = (int)xf, y0i = (int)yf;
                const float wx = x - xf, wy = y - yf;
                const float aw = al[l * 4 + p] * inv;
#pragma unroll
                for (int cy = 0; cy < 2; ++cy) {
#pragma unroll
                    for (int cx = 0; cx < 2; ++cx) {
                        const int xi = x0i + cx, yi = y0i + cy;
                        const bool valid =
                            (xi >= 0) & (xi < Wl) & (yi >= 0) & (yi < Hl);
                        const int xc = min(max(xi, 0), Wl - 1);
                        const int yc = min(max(yi, 0), Hl - 1);
                        const float w = aw * (cx ? wx : 1.f - wx)
                                           * (cy ? wy : 1.f - wy);
                        cidx[p * 4 + cy * 2 + cx] = yc * Wl + xc;
                        cwt [p * 4 + cy * 2 + cx] = valid ? w : 0.f;
                    }
                }
            }
            // 16 independent coalesced wave-loads (1KB each), then FMAs
#pragma unroll
            for (int k = 0; k < 16; ++k) {
                const float4 vvv = *(const float4*)(vb +
                    (size_t)cidx[k] * 256 + lane * 4);
                const float cw = cwt[k];
                o0 = fmaf(cw, vvv.x, o0);
                o1 = fmaf(cw, vvv.y, o1);
                o2 = fmaf(cw, vvv.z, o2);
                o3 = fmaf(cw, vvv.w, o3);
            }
        }

        *(float4*)(outp + (size_t)row * 256 + lane * 4) =
            make_float4(o0, o1, o2, o3);
    }
}

// ---------------------------------------------------------------------------
// K3: output projection.
// ---------------------------------------------------------------------------
__global__ __launch_bounds__(256) void outproj_kernel(
    const float* __restrict__ A, const float* __restrict__ Wo,
    const float* __restrict__ bo, float* __restrict__ out)
{
    __shared__ float As[16 * 68];    // [kk][r]
    __shared__ float Ws[16 * 256];

    const int row0 = blockIdx.x * 64;
    const int tid  = threadIdx.x;
    const int tp   = tid >> 5;
    const int tc   = tid & 31;

    float acc[8][8];
#pragma unroll
    for (int i = 0; i < 8; ++i)
#pragma unroll
        for (int j = 0; j < 8; ++j) acc[i][j] = 0.f;

    for (int k0 = 0; k0 < 256; k0 += 16) {
        {
            const int r  = tid >> 2;
            const int kq = (tid & 3) * 4;
            const float4 av =
                *(const float4*)&A[(size_t)(row0 + r) * 256 + k0 + kq];
            As[(kq + 0) * 68 + r] = av.x;
            As[(kq + 1) * 68 + r] = av.y;
            As[(kq + 2) * 68 + r] = av.z;
            As[(kq + 3) * 68 + r] = av.w;
        }
#pragma unroll
        for (int kk = 0; kk < 16; ++kk)
            Ws[kk * 256 + tid] = Wo[(size_t)(k0 + kk) * 256 + tid];
        __syncthreads();

#pragma unroll
        for (int kk = 0; kk < 16; ++kk) {
            const float4 a0 = *(const float4*)&As[kk * 68 + tp * 8];
            const float4 a1 = *(const float4*)&As[kk * 68 + tp * 8 + 4];
            const float a[8] = {a0.x, a0.y, a0.z, a0.w, a1.x, a1.y, a1.z, a1.w};
            float w[8];
#pragma unroll
            for (int j = 0; j < 8; ++j) w[j] = Ws[kk * 256 + tc + 32 * j];
#pragma unroll
            for (int i = 0; i < 8; ++i)
#pragma unroll
                for (int j = 0; j < 8; ++j)
                    acc[i][j] = fmaf(a[i], w[j], acc[i][j]);
        }
        __syncthreads();
    }

    float bb[8];
#pragma unroll
    for (int j = 0; j < 8; ++j) bb[j] = bo[tc + 32 * j];

#pragma unroll
    for (int i = 0; i < 8; ++i) {
        const int r = row0 + tp * 8 + i;
#pragma unroll
        for (int j = 0; j < 8; ++j)
            out[(size_t)r * 256 + tc + 32 * j] = acc[i][j] + bb[j];
    }
}

// ---------------------------------------------------------------------------
extern "C" void kernel_launch(void* const* d_in, const int* in_sizes, int n_in,
                              void* d_out, int out_size, void* d_ws, size_t ws_size,
                              hipStream_t stream)
{
    const float* query  = (const float*)d_in[0];
    const float* value0 = (const float*)d_in[1];
    const float* value1 = (const float*)d_in[2];
    const float* value2 = (const float*)d_in[3];
    const float* refpts = (const float*)d_in[4];
    const float* Woff   = (const float*)d_in[5];
    const float* boff   = (const float*)d_in[6];
    const float* Wattn  = (const float*)d_in[7];
    const float* battn  = (const float*)d_in[8];
    const float* Wval   = (const float*)d_in[9];
    const float* bval   = (const float*)d_in[10];
    const float* Wout   = (const float*)d_in[11];
    const float* bout   = (const float*)d_in[12];
    float* out = (float*)d_out;

    float* ws = (float*)d_ws;
    float* v0   = ws;                                        // 4*10000*256
    float* v1   = v0 + (size_t)BATCH * 10000 * 256;          // 4*2500*256
    float* v2   = v1 + (size_t)BATCH * 2500  * 256;          // 4*625*256
    float* outp = v2 + (size_t)BATCH * 625   * 256;          // 40000*256

    vproj_kernel<<<dim3(157, BATCH), 256, 0, stream>>>(value0, Wval, bval, v0, 10000);
    vproj_kernel<<<dim3(40,  BATCH), 256, 0, stream>>>(value1, Wval, bval, v1, 2500);
    vproj_kernel<<<dim3(10,  BATCH), 256, 0, stream>>>(value2, Wval, bval, v2, 625);

    qsamp_kernel<<<1250, 256, 0, stream>>>(query, refpts, Woff, boff,
                                           Wattn, battn, v0, v1, v2, outp);

    outproj_kernel<<<625, 256, 0, stream>>>(outp, Wout, bout, out);
}

// Round 3
// 852.921 us; speedup vs baseline: 1.1832x; 1.0962x over previous
//
#include <hip/hip_runtime.h>
#include <math.h>

#define DMODEL 256
#define NHEAD 8
#define NLVL 3
#define NPTS 4
#define HDIM 32
#define QLEN 10000
#define BATCH 4
#define NQ (BATCH * QLEN)

__device__ __forceinline__ float tanh_fast(float x)
{
    const float ax = fabsf(x);
    const float e  = __expf(-2.f * ax);
    const float t  = (1.f - e) / (1.f + e);
    return copysignf(t, x);
}

__device__ __forceinline__ unsigned short f2bf(float f)
{
    unsigned int u = __float_as_uint(f);
    u = (u + 0x7FFFu + ((u >> 16) & 1u)) >> 16;
    return (unsigned short)u;
}

__device__ __forceinline__ float bf2f(unsigned short s)
{
    return __uint_as_float(((unsigned int)s) << 16);
}

// ---------------------------------------------------------------------------
// K1: value projection -> bf16.  v[b][pos][c] = sum_k feat[b][k][pos]*Wv[k][c]+bv[c]
// Thread tc owns column pairs (2tc + 64j), j=0..3 -> packed uint (2xbf16) stores.
// ---------------------------------------------------------------------------
__global__ __launch_bounds__(256) void vproj_kernel(
    const float* __restrict__ feat, const float* __restrict__ Wv,
    const float* __restrict__ bv, unsigned short* __restrict__ vout, int HW)
{
    __shared__ float As[16 * 64];    // [kk][pos]
    __shared__ float Ws[16 * 256];   // [kk][col]

    const int b    = blockIdx.y;
    const int pos0 = blockIdx.x * 64;
    const int tid  = threadIdx.x;
    const int tp   = tid >> 5;
    const int tc   = tid & 31;

    float acc[8][8];
#pragma unroll
    for (int i = 0; i < 8; ++i)
#pragma unroll
        for (int j = 0; j < 8; ++j) acc[i][j] = 0.f;

    const float* fb = feat + (size_t)b * DMODEL * HW;

    for (int k0 = 0; k0 < 256; k0 += 16) {
#pragma unroll
        for (int it = 0; it < 4; ++it) {
            const int kk = (tid >> 6) + it * 4;
            const int p  = tid & 63;
            float va = 0.f;
            if (pos0 + p < HW) va = fb[(size_t)(k0 + kk) * HW + pos0 + p];
            As[kk * 64 + p] = va;
        }
#pragma unroll
        for (int kk = 0; kk < 16; ++kk)
            Ws[kk * 256 + tid] = Wv[(size_t)(k0 + kk) * 256 + tid];
        __syncthreads();

#pragma unroll
        for (int kk = 0; kk < 16; ++kk) {
            const float4 a0 = *(const float4*)&As[kk * 64 + tp * 8];
            const float4 a1 = *(const float4*)&As[kk * 64 + tp * 8 + 4];
            const float a[8] = {a0.x, a0.y, a0.z, a0.w, a1.x, a1.y, a1.z, a1.w};
            float w[8];
#pragma unroll
            for (int jj = 0; jj < 4; ++jj) {
                const float2 wv = *(const float2*)&Ws[kk * 256 + 2 * tc + 64 * jj];
                w[2 * jj]     = wv.x;
                w[2 * jj + 1] = wv.y;
            }
#pragma unroll
            for (int i = 0; i < 8; ++i)
#pragma unroll
                for (int j = 0; j < 8; ++j)
                    acc[i][j] = fmaf(a[i], w[j], acc[i][j]);
        }
        __syncthreads();
    }

    float bb[8];
#pragma unroll
    for (int jj = 0; jj < 4; ++jj) {
        const float2 bvv = *(const float2*)&bv[2 * tc + 64 * jj];
        bb[2 * jj]     = bvv.x;
        bb[2 * jj + 1] = bvv.y;
    }

    unsigned short* vb = vout + (size_t)b * HW * 256;
#pragma unroll
    for (int i = 0; i < 8; ++i) {
        const int p = pos0 + tp * 8 + i;
        if (p < HW) {
            unsigned int* vp = (unsigned int*)(vb + (size_t)p * 256);
#pragma unroll
            for (int jj = 0; jj < 4; ++jj) {
                const unsigned int lo = f2bf(acc[i][2 * jj]     + bb[2 * jj]);
                const unsigned int hi = f2bf(acc[i][2 * jj + 1] + bb[2 * jj + 1]);
                vp[tc + 32 * jj] = lo | (hi << 16);
            }
        }
    }
}

// ---------------------------------------------------------------------------
// K2: query-side GEMM (logits[32][288]) + epilogue computing per-(q,h,l,p)
//     sampling params: x, y (pixel coords) and softmaxed attention weight.
//     params layout: [q][h*12 + l*4 + p][3]  (288 floats per query)
// ---------------------------------------------------------------------------
__global__ __launch_bounds__(256) void qparam_kernel(
    const float* __restrict__ query, const float* __restrict__ ref,
    const float* __restrict__ Woff, const float* __restrict__ boff,
    const float* __restrict__ Wattn, const float* __restrict__ battn,
    float* __restrict__ params)
{
    __shared__ float Qs[16 * 36];      // [kk][r]
    __shared__ float SH[32 * 288];     // W-tile during GEMM, then logits[32][288]
    float* WL = SH;
    float* LG = SH;

    const int row0 = blockIdx.x * 32;
    const int tid  = threadIdx.x;
    const int tp   = tid >> 5;
    const int tc   = tid & 31;

    float acc[4][9];
#pragma unroll
    for (int i = 0; i < 4; ++i)
#pragma unroll
        for (int j = 0; j < 9; ++j) acc[i][j] = 0.f;

    for (int k0 = 0; k0 < 256; k0 += 16) {
        if (tid < 128) {
            const int r  = tid >> 2;
            const int kq = (tid & 3) * 4;
            const float4 qv =
                *(const float4*)&query[(size_t)(row0 + r) * 256 + k0 + kq];
            Qs[(kq + 0) * 36 + r] = qv.x;
            Qs[(kq + 1) * 36 + r] = qv.y;
            Qs[(kq + 2) * 36 + r] = qv.z;
            Qs[(kq + 3) * 36 + r] = qv.w;
        }
#pragma unroll
        for (int kk = 0; kk < 16; ++kk) {
            for (int n = tid; n < 288; n += 256) {
                const float wv = (n < 192)
                    ? Woff[(size_t)(k0 + kk) * 192 + n]
                    : Wattn[(size_t)(k0 + kk) * 96 + (n - 192)];
                WL[kk * 288 + n] = wv;
            }
        }
        __syncthreads();

#pragma unroll
        for (int kk = 0; kk < 16; ++kk) {
            const float4 av = *(const float4*)&Qs[kk * 36 + tp * 4];
            const float a[4] = {av.x, av.y, av.z, av.w};
            float w[9];
#pragma unroll
            for (int j = 0; j < 9; ++j) w[j] = WL[kk * 288 + tc + 32 * j];
#pragma unroll
            for (int i = 0; i < 4; ++i)
#pragma unroll
                for (int j = 0; j < 9; ++j)
                    acc[i][j] = fmaf(a[i], w[j], acc[i][j]);
        }
        __syncthreads();
    }

#pragma unroll
    for (int j = 0; j < 9; ++j) {
        const int col = tc + 32 * j;
        const float bias = (col < 192) ? boff[col] : battn[col - 192];
#pragma unroll
        for (int i = 0; i < 4; ++i)
            LG[(tp * 4 + i) * 288 + col] = acc[i][j] + bias;
    }
    __syncthreads();

    // epilogue: one thread per (q,h)
    const int qs  = tid >> 3;
    const int h   = tid & 7;
    const int row = row0 + qs;
    const float* lg = &LG[qs * 288];

    float al[12];
#pragma unroll
    for (int j = 0; j < 12; ++j) al[j] = lg[192 + h * 12 + j];
    float m = al[0];
#pragma unroll
    for (int j = 1; j < 12; ++j) m = fmaxf(m, al[j]);
    float s = 0.f;
#pragma unroll
    for (int j = 0; j < 12; ++j) { al[j] = __expf(al[j] - m); s += al[j]; }
    const float inv = 1.f / s;

    const float refx = ref[(size_t)row * 2 + 0];
    const float refy = ref[(size_t)row * 2 + 1];

    float outv[36];
#pragma unroll
    for (int l = 0; l < 3; ++l) {
        const float Wl = (l == 0) ? 100.f : (l == 1) ? 50.f : 25.f;
#pragma unroll
        for (int p = 0; p < 4; ++p) {
            const int j = l * 4 + p;
            const float ox = 0.5f * tanh_fast(lg[h * 24 + l * 8 + p * 2 + 0]);
            const float oy = 0.5f * tanh_fast(lg[h * 24 + l * 8 + p * 2 + 1]);
            outv[3 * j + 0] = (refx + ox) * Wl - 0.5f;
            outv[3 * j + 1] = (refy + oy) * Wl - 0.5f;
            outv[3 * j + 2] = al[j] * inv;
        }
    }

    float4* pp = (float4*)(params + (size_t)row * 288 + h * 36);
#pragma unroll
    for (int i = 0; i < 9; ++i)
        pp[i] = make_float4(outv[4 * i + 0], outv[4 * i + 1],
                            outv[4 * i + 2], outv[4 * i + 3]);
}

// ---------------------------------------------------------------------------
// K3: sampler.  ONE WAVE = ONE QUERY (no serialization, no LDS).
// lane = 8*h + qd; per corner the wave issues one 8B/lane bf16 load:
// 8 coalesced 64B segments.
// ---------------------------------------------------------------------------
__global__ __launch_bounds__(256) void sample_kernel(
    const float* __restrict__ params,
    const unsigned short* __restrict__ v0,
    const unsigned short* __restrict__ v1,
    const unsigned short* __restrict__ v2,
    float* __restrict__ outp)
{
    const int tid  = threadIdx.x;
    const int lane = tid & 63;
    const int q    = blockIdx.x * 4 + (tid >> 6);
    const int h    = lane >> 3;
    const int qd   = lane & 7;
    const int b    = q / QLEN;

    // load this head's 36 params (9 float4, broadcast within 8-lane group)
    const float4* pp = (const float4*)(params + (size_t)q * 288 + h * 36);
    float f[36];
#pragma unroll
    for (int i = 0; i < 9; ++i) {
        const float4 v = pp[i];
        f[4 * i + 0] = v.x; f[4 * i + 1] = v.y;
        f[4 * i + 2] = v.z; f[4 * i + 3] = v.w;
    }

    float o0 = 0.f, o1 = 0.f, o2 = 0.f, o3 = 0.f;

#pragma unroll
    for (int l = 0; l < 3; ++l) {
        const int Wl = (l == 0) ? 100 : (l == 1) ? 50 : 25;
        const int Hl = Wl;
        const unsigned short* vb =
            (l == 0) ? v0 + (size_t)b * 10000 * 256 :
            (l == 1) ? v1 + (size_t)b * 2500  * 256 :
                       v2 + (size_t)b * 625   * 256;

        int   cidx[16];
        float cwt[16];
#pragma unroll
        for (int p = 0; p < 4; ++p) {
            const int j = l * 4 + p;
            const float x  = f[3 * j + 0];
            const float y  = f[3 * j + 1];
            const float aw = f[3 * j + 2];
            const float xf = floorf(x), yf = floorf(y);
            const int   x0i = (int)xf, y0i = (int)yf;
            const float wx = x - xf, wy = y - yf;
#pragma unroll
            for (int cy = 0; cy < 2; ++cy) {
#pragma unroll
                for (int cx = 0; cx < 2; ++cx) {
                    const int xi = x0i + cx, yi = y0i + cy;
                    const bool valid =
                        (xi >= 0) & (xi < Wl) & (yi >= 0) & (yi < Hl);
                    const int xc = min(max(xi, 0), Wl - 1);
                    const int yc = min(max(yi, 0), Hl - 1);
                    const float w = aw * (cx ? wx : 1.f - wx)
                                       * (cy ? wy : 1.f - wy);
                    cidx[p * 4 + cy * 2 + cx] = yc * Wl + xc;
                    cwt [p * 4 + cy * 2 + cx] = valid ? w : 0.f;
                }
            }
        }
#pragma unroll
        for (int k = 0; k < 16; ++k) {
            const ushort4 u = *(const ushort4*)(vb +
                (size_t)cidx[k] * 256 + h * 32 + qd * 4);
            const float cw = cwt[k];
            o0 = fmaf(cw, bf2f(u.x), o0);
            o1 = fmaf(cw, bf2f(u.y), o1);
            o2 = fmaf(cw, bf2f(u.z), o2);
            o3 = fmaf(cw, bf2f(u.w), o3);
        }
    }

    *(float4*)(outp + (size_t)q * 256 + lane * 4) = make_float4(o0, o1, o2, o3);
}

// ---------------------------------------------------------------------------
// K4: output projection (IN-PLACE on d_out: each block writes only rows it
// alone reads, and only after its final k-step).
// ---------------------------------------------------------------------------
__global__ __launch_bounds__(256) void outproj_kernel(
    const float* __restrict__ A, const float* __restrict__ Wo,
    const float* __restrict__ bo, float* __restrict__ out)
{
    __shared__ float As[16 * 68];    // [kk][r]
    __shared__ float Ws[16 * 256];

    const int row0 = blockIdx.x * 64;
    const int tid  = threadIdx.x;
    const int tp   = tid >> 5;
    const int tc   = tid & 31;

    float acc[8][8];
#pragma unroll
    for (int i = 0; i < 8; ++i)
#pragma unroll
        for (int j = 0; j < 8; ++j) acc[i][j] = 0.f;

    for (int k0 = 0; k0 < 256; k0 += 16) {
        {
            const int r  = tid >> 2;
            const int kq = (tid & 3) * 4;
            const float4 av =
                *(const float4*)&A[(size_t)(row0 + r) * 256 + k0 + kq];
            As[(kq + 0) * 68 + r] = av.x;
            As[(kq + 1) * 68 + r] = av.y;
            As[(kq + 2) * 68 + r] = av.z;
            As[(kq + 3) * 68 + r] = av.w;
        }
#pragma unroll
        for (int kk = 0; kk < 16; ++kk)
            Ws[kk * 256 + tid] = Wo[(size_t)(k0 + kk) * 256 + tid];
        __syncthreads();

#pragma unroll
        for (int kk = 0; kk < 16; ++kk) {
            const float4 a0 = *(const float4*)&As[kk * 68 + tp * 8];
            const float4 a1 = *(const float4*)&As[kk * 68 + tp * 8 + 4];
            const float a[8] = {a0.x, a0.y, a0.z, a0.w, a1.x, a1.y, a1.z, a1.w};
            float w[8];
#pragma unroll
            for (int j = 0; j < 8; ++j) w[j] = Ws[kk * 256 + tc + 32 * j];
#pragma unroll
            for (int i = 0; i < 8; ++i)
#pragma unroll
                for (int j = 0; j < 8; ++j)
                    acc[i][j] = fmaf(a[i], w[j], acc[i][j]);
        }
        __syncthreads();
    }

    float bb[8];
#pragma unroll
    for (int j = 0; j < 8; ++j) bb[j] = bo[tc + 32 * j];

#pragma unroll
    for (int i = 0; i < 8; ++i) {
        const int r = row0 + tp * 8 + i;
#pragma unroll
        for (int j = 0; j < 8; ++j)
            out[(size_t)r * 256 + tc + 32 * j] = acc[i][j] + bb[j];
    }
}

// ---------------------------------------------------------------------------
extern "C" void kernel_launch(void* const* d_in, const int* in_sizes, int n_in,
                              void* d_out, int out_size, void* d_ws, size_t ws_size,
                              hipStream_t stream)
{
    const float* query  = (const float*)d_in[0];
    const float* value0 = (const float*)d_in[1];
    const float* value1 = (const float*)d_in[2];
    const float* value2 = (const float*)d_in[3];
    const float* refpts = (const float*)d_in[4];
    const float* Woff   = (const float*)d_in[5];
    const float* boff   = (const float*)d_in[6];
    const float* Wattn  = (const float*)d_in[7];
    const float* battn  = (const float*)d_in[8];
    const float* Wval   = (const float*)d_in[9];
    const float* bval   = (const float*)d_in[10];
    const float* Wout   = (const float*)d_in[11];
    const float* bout   = (const float*)d_in[12];
    float* out = (float*)d_out;

    // workspace layout (bytes):
    //   params : NQ*288 f32                      = 46.08 MB
    //   v0     : 4*10000*256 bf16                = 20.48 MB
    //   v1     : 4*2500*256  bf16                =  5.12 MB
    //   v2     : 4*625*256   bf16                =  1.28 MB
    // pre-projection sample output lives IN d_out (outproj is in-place).
    float*          params = (float*)d_ws;
    unsigned short* v0 = (unsigned short*)(params + (size_t)NQ * 288);
    unsigned short* v1 = v0 + (size_t)BATCH * 10000 * 256;
    unsigned short* v2 = v1 + (size_t)BATCH * 2500  * 256;
    float*          outp = out;

    vproj_kernel<<<dim3(157, BATCH), 256, 0, stream>>>(value0, Wval, bval, v0, 10000);
    vproj_kernel<<<dim3(40,  BATCH), 256, 0, stream>>>(value1, Wval, bval, v1, 2500);
    vproj_kernel<<<dim3(10,  BATCH), 256, 0, stream>>>(value2, Wval, bval, v2, 625);

    qparam_kernel<<<1250, 256, 0, stream>>>(query, refpts, Woff, boff,
                                            Wattn, battn, params);

    sample_kernel<<<NQ / 4, 256, 0, stream>>>(params, v0, v1, v2, outp);

    outproj_kernel<<<625, 256, 0, stream>>>(outp, Wout, bout, out);
}

// Round 4
// 411.128 us; speedup vs baseline: 2.4547x; 2.0746x over previous
//
#include <hip/hip_runtime.h>
#include <math.h>

#define DMODEL 256
#define NHEAD 8
#define NLVL 3
#define NPTS 4
#define HDIM 32
#define QLEN 10000
#define BATCH 4
#define NQ (BATCH * QLEN)

__device__ __forceinline__ float tanh_fast(float x)
{
    const float ax = fabsf(x);
    const float e  = __expf(-2.f * ax);
    const float t  = (1.f - e) / (1.f + e);
    return copysignf(t, x);
}

__device__ __forceinline__ unsigned short f2bf(float f)
{
    unsigned int u = __float_as_uint(f);
    u = (u + 0x7FFFu + ((u >> 16) & 1u)) >> 16;
    return (unsigned short)u;
}

__device__ __forceinline__ float bf2f(unsigned short s)
{
    return __uint_as_float(((unsigned int)s) << 16);
}

// ---------------------------------------------------------------------------
// K1: value projection -> bf16, all 3 levels in one grid.
// v[b][pos][c] = sum_k feat[b][k][pos]*Wv[k][c]+bv[c]
// ---------------------------------------------------------------------------
__global__ __launch_bounds__(256) void vproj_kernel(
    const float* __restrict__ feat0, const float* __restrict__ feat1,
    const float* __restrict__ feat2, const float* __restrict__ Wv,
    const float* __restrict__ bv,
    unsigned short* __restrict__ v0, unsigned short* __restrict__ v1,
    unsigned short* __restrict__ v2)
{
    __shared__ float As[16 * 64];    // [kk][pos]
    __shared__ float Ws[16 * 256];   // [kk][col]

    const int bx = blockIdx.x;
    const int b  = blockIdx.y;

    const float* feat;
    unsigned short* vout;
    int HW, pos0;
    if (bx < 157)      { feat = feat0; vout = v0; HW = 10000; pos0 = bx * 64; }
    else if (bx < 197) { feat = feat1; vout = v1; HW = 2500;  pos0 = (bx - 157) * 64; }
    else               { feat = feat2; vout = v2; HW = 625;   pos0 = (bx - 197) * 64; }

    const int tid  = threadIdx.x;
    const int tp   = tid >> 5;
    const int tc   = tid & 31;

    float acc[8][8];
#pragma unroll
    for (int i = 0; i < 8; ++i)
#pragma unroll
        for (int j = 0; j < 8; ++j) acc[i][j] = 0.f;

    const float* fb = feat + (size_t)b * DMODEL * HW;

    for (int k0 = 0; k0 < 256; k0 += 16) {
#pragma unroll
        for (int it = 0; it < 4; ++it) {
            const int kk = (tid >> 6) + it * 4;
            const int p  = tid & 63;
            float va = 0.f;
            if (pos0 + p < HW) va = fb[(size_t)(k0 + kk) * HW + pos0 + p];
            As[kk * 64 + p] = va;
        }
#pragma unroll
        for (int kk = 0; kk < 16; ++kk)
            Ws[kk * 256 + tid] = Wv[(size_t)(k0 + kk) * 256 + tid];
        __syncthreads();

#pragma unroll
        for (int kk = 0; kk < 16; ++kk) {
            const float4 a0 = *(const float4*)&As[kk * 64 + tp * 8];
            const float4 a1 = *(const float4*)&As[kk * 64 + tp * 8 + 4];
            const float a[8] = {a0.x, a0.y, a0.z, a0.w, a1.x, a1.y, a1.z, a1.w};
            float w[8];
#pragma unroll
            for (int jj = 0; jj < 4; ++jj) {
                const float2 wv = *(const float2*)&Ws[kk * 256 + 2 * tc + 64 * jj];
                w[2 * jj]     = wv.x;
                w[2 * jj + 1] = wv.y;
            }
#pragma unroll
            for (int i = 0; i < 8; ++i)
#pragma unroll
                for (int j = 0; j < 8; ++j)
                    acc[i][j] = fmaf(a[i], w[j], acc[i][j]);
        }
        __syncthreads();
    }

    float bb[8];
#pragma unroll
    for (int jj = 0; jj < 4; ++jj) {
        const float2 bvv = *(const float2*)&bv[2 * tc + 64 * jj];
        bb[2 * jj]     = bvv.x;
        bb[2 * jj + 1] = bvv.y;
    }

    unsigned short* vb = vout + (size_t)b * HW * 256;
#pragma unroll
    for (int i = 0; i < 8; ++i) {
        const int p = pos0 + tp * 8 + i;
        if (p < HW) {
            unsigned int* vp = (unsigned int*)(vb + (size_t)p * 256);
#pragma unroll
            for (int jj = 0; jj < 4; ++jj) {
                const unsigned int lo = f2bf(acc[i][2 * jj]     + bb[2 * jj]);
                const unsigned int hi = f2bf(acc[i][2 * jj + 1] + bb[2 * jj + 1]);
                vp[tc + 32 * jj] = lo | (hi << 16);
            }
        }
    }
}

// ---------------------------------------------------------------------------
// K2: query-side GEMM + epilogue, head-owner decomposition.
// 64 rows/block, 256 threads: thread = (r0 = tid>>3 in 0..31, h = tid&7),
// owns rows {r0, r0+32} with acc[2][36] = head-h's 24 offset + 12 attn logits.
// W staged in LDS with head-permuted layout: head h's 36 cols contiguous.
// Epilogue fully in registers -> params[q][h*36 + 3*(l*4+p) + {x,y,aw}].
// ---------------------------------------------------------------------------
__global__ __launch_bounds__(256) void qparam_kernel(
    const float* __restrict__ query, const float* __restrict__ ref,
    const float* __restrict__ Woff, const float* __restrict__ boff,
    const float* __restrict__ Wattn, const float* __restrict__ battn,
    float* __restrict__ params)
{
    __shared__ float Qs[16 * 68];    // [kk][r], stride 68
    __shared__ float WL[16 * 288];   // [kk][permuted col]: head h -> [h*36..h*36+35]

    const int row0 = blockIdx.x * 64;
    const int tid  = threadIdx.x;
    const int h    = tid & 7;
    const int r0   = tid >> 3;       // 0..31

    float acc[2][36];
#pragma unroll
    for (int i = 0; i < 2; ++i)
#pragma unroll
        for (int j = 0; j < 36; ++j) acc[i][j] = 0.f;

    // Q staging indices (fixed per thread)
    const int sr = tid >> 2;          // 0..63
    const int sk = (tid & 3) * 4;     // 0,4,8,12

    for (int k0 = 0; k0 < 256; k0 += 16) {
        // ---- stage Q[64][16] transposed ----
        {
            const float4 qv =
                *(const float4*)&query[(size_t)(row0 + sr) * 256 + k0 + sk];
            Qs[(sk + 0) * 68 + sr] = qv.x;
            Qs[(sk + 1) * 68 + sr] = qv.y;
            Qs[(sk + 2) * 68 + sr] = qv.z;
            Qs[(sk + 3) * 68 + sr] = qv.w;
        }
        // ---- stage W[16][288] as float4, head-permuted ----
#pragma unroll
        for (int j = 0; j < 5; ++j) {
            const int g = tid + j * 256;           // float4 index, 0..1151
            if (j < 4 || g < 1152) {
                const int kk = g / 72;
                const int c4 = g - kk * 72;        // float4 within row (72 per row)
                float4 wv;
                int dpos;
                if (c4 < 48) {                     // W_off: col c = 4*c4 in 0..191
                    const int c  = 4 * c4;
                    const int hh = c / 24;
                    wv   = *(const float4*)&Woff[(size_t)(k0 + kk) * 192 + c];
                    dpos = hh * 36 + (c - hh * 24);
                } else {                           // W_attn: col m = 4*(c4-48) in 0..95
                    const int m  = 4 * (c4 - 48);
                    const int hh = m / 12;
                    wv   = *(const float4*)&Wattn[(size_t)(k0 + kk) * 96 + m];
                    dpos = hh * 36 + 24 + (m - hh * 12);
                }
                *(float4*)&WL[kk * 288 + dpos] = wv;
            }
        }
        __syncthreads();

        // ---- FMA: 72 per kk ----
#pragma unroll
        for (int kk = 0; kk < 16; ++kk) {
            const float a0 = Qs[kk * 68 + r0];
            const float a1 = Qs[kk * 68 + r0 + 32];
            const float* wp = &WL[kk * 288 + h * 36];
#pragma unroll
            for (int u = 0; u < 9; ++u) {
                const float4 w4 = *(const float4*)&wp[4 * u];
                acc[0][4 * u + 0] = fmaf(a0, w4.x, acc[0][4 * u + 0]);
                acc[0][4 * u + 1] = fmaf(a0, w4.y, acc[0][4 * u + 1]);
                acc[0][4 * u + 2] = fmaf(a0, w4.z, acc[0][4 * u + 2]);
                acc[0][4 * u + 3] = fmaf(a0, w4.w, acc[0][4 * u + 3]);
                acc[1][4 * u + 0] = fmaf(a1, w4.x, acc[1][4 * u + 0]);
                acc[1][4 * u + 1] = fmaf(a1, w4.y, acc[1][4 * u + 1]);
                acc[1][4 * u + 2] = fmaf(a1, w4.z, acc[1][4 * u + 2]);
                acc[1][4 * u + 3] = fmaf(a1, w4.w, acc[1][4 * u + 3]);
            }
        }
        __syncthreads();
    }

    // ---- epilogue (registers only) ----
#pragma unroll
    for (int i = 0; i < 2; ++i) {
        const int row = row0 + r0 + 32 * i;
        float* lg = acc[i];

        // biases
#pragma unroll
        for (int j = 0; j < 24; ++j) lg[j] += boff[h * 24 + j];
#pragma unroll
        for (int j = 0; j < 12; ++j) lg[24 + j] += battn[h * 12 + j];

        // softmax over attn logits
        float m = lg[24];
#pragma unroll
        for (int j = 1; j < 12; ++j) m = fmaxf(m, lg[24 + j]);
        float s = 0.f;
        float al[12];
#pragma unroll
        for (int j = 0; j < 12; ++j) { al[j] = __expf(lg[24 + j] - m); s += al[j]; }
        const float inv = 1.f / s;

        const float refx = ref[(size_t)row * 2 + 0];
        const float refy = ref[(size_t)row * 2 + 1];

        float outv[36];
#pragma unroll
        for (int l = 0; l < 3; ++l) {
            const float Wl = (l == 0) ? 100.f : (l == 1) ? 50.f : 25.f;
#pragma unroll
            for (int p = 0; p < 4; ++p) {
                const int j = l * 4 + p;
                const float ox = 0.5f * tanh_fast(lg[l * 8 + p * 2 + 0]);
                const float oy = 0.5f * tanh_fast(lg[l * 8 + p * 2 + 1]);
                outv[3 * j + 0] = (refx + ox) * Wl - 0.5f;
                outv[3 * j + 1] = (refy + oy) * Wl - 0.5f;
                outv[3 * j + 2] = al[j] * inv;
            }
        }

        float4* pp = (float4*)(params + (size_t)row * 288 + h * 36);
#pragma unroll
        for (int u = 0; u < 9; ++u)
            pp[u] = make_float4(outv[4 * u + 0], outv[4 * u + 1],
                                outv[4 * u + 2], outv[4 * u + 3]);
    }
}

// ---------------------------------------------------------------------------
// K3: sampler.  ONE WAVE = ONE QUERY.
// ---------------------------------------------------------------------------
__global__ __launch_bounds__(256) void sample_kernel(
    const float* __restrict__ params,
    const unsigned short* __restrict__ v0,
    const unsigned short* __restrict__ v1,
    const unsigned short* __restrict__ v2,
    float* __restrict__ outp)
{
    const int tid  = threadIdx.x;
    const int lane = tid & 63;
    const int q    = blockIdx.x * 4 + (tid >> 6);
    const int h    = lane >> 3;
    const int qd   = lane & 7;
    const int b    = q / QLEN;

    const float4* pp = (const float4*)(params + (size_t)q * 288 + h * 36);
    float f[36];
#pragma unroll
    for (int i = 0; i < 9; ++i) {
        const float4 v = pp[i];
        f[4 * i + 0] = v.x; f[4 * i + 1] = v.y;
        f[4 * i + 2] = v.z; f[4 * i + 3] = v.w;
    }

    float o0 = 0.f, o1 = 0.f, o2 = 0.f, o3 = 0.f;

#pragma unroll
    for (int l = 0; l < 3; ++l) {
        const int Wl = (l == 0) ? 100 : (l == 1) ? 50 : 25;
        const int Hl = Wl;
        const unsigned short* vb =
            (l == 0) ? v0 + (size_t)b * 10000 * 256 :
            (l == 1) ? v1 + (size_t)b * 2500  * 256 :
                       v2 + (size_t)b * 625   * 256;

        int   cidx[16];
        float cwt[16];
#pragma unroll
        for (int p = 0; p < 4; ++p) {
            const int j = l * 4 + p;
            const float x  = f[3 * j + 0];
            const float y  = f[3 * j + 1];
            const float aw = f[3 * j + 2];
            const float xf = floorf(x), yf = floorf(y);
            const int   x0i = (int)xf, y0i = (int)yf;
            const float wx = x - xf, wy = y - yf;
#pragma unroll
            for (int cy = 0; cy < 2; ++cy) {
#pragma unroll
                for (int cx = 0; cx < 2; ++cx) {
                    const int xi = x0i + cx, yi = y0i + cy;
                    const bool valid =
                        (xi >= 0) & (xi < Wl) & (yi >= 0) & (yi < Hl);
                    const int xc = min(max(xi, 0), Wl - 1);
                    const int yc = min(max(yi, 0), Hl - 1);
                    const float w = aw * (cx ? wx : 1.f - wx)
                                       * (cy ? wy : 1.f - wy);
                    cidx[p * 4 + cy * 2 + cx] = yc * Wl + xc;
                    cwt [p * 4 + cy * 2 + cx] = valid ? w : 0.f;
                }
            }
        }
#pragma unroll
        for (int k = 0; k < 16; ++k) {
            const ushort4 u = *(const ushort4*)(vb +
                (size_t)cidx[k] * 256 + h * 32 + qd * 4);
            const float cw = cwt[k];
            o0 = fmaf(cw, bf2f(u.x), o0);
            o1 = fmaf(cw, bf2f(u.y), o1);
            o2 = fmaf(cw, bf2f(u.z), o2);
            o3 = fmaf(cw, bf2f(u.w), o3);
        }
    }

    *(float4*)(outp + (size_t)q * 256 + lane * 4) = make_float4(o0, o1, o2, o3);
}

// ---------------------------------------------------------------------------
// K4: output projection (in-place on d_out).
// ---------------------------------------------------------------------------
__global__ __launch_bounds__(256) void outproj_kernel(
    const float* __restrict__ A, const float* __restrict__ Wo,
    const float* __restrict__ bo, float* __restrict__ out)
{
    __shared__ float As[16 * 68];    // [kk][r]
    __shared__ float Ws[16 * 256];

    const int row0 = blockIdx.x * 64;
    const int tid  = threadIdx.x;
    const int tp   = tid >> 5;
    const int tc   = tid & 31;

    float acc[8][8];
#pragma unroll
    for (int i = 0; i < 8; ++i)
#pragma unroll
        for (int j = 0; j < 8; ++j) acc[i][j] = 0.f;

    for (int k0 = 0; k0 < 256; k0 += 16) {
        {
            const int r  = tid >> 2;
            const int kq = (tid & 3) * 4;
            const float4 av =
                *(const float4*)&A[(size_t)(row0 + r) * 256 + k0 + kq];
            As[(kq + 0) * 68 + r] = av.x;
            As[(kq + 1) * 68 + r] = av.y;
            As[(kq + 2) * 68 + r] = av.z;
            As[(kq + 3) * 68 + r] = av.w;
        }
#pragma unroll
        for (int kk = 0; kk < 16; ++kk)
            Ws[kk * 256 + tid] = Wo[(size_t)(k0 + kk) * 256 + tid];
        __syncthreads();

#pragma unroll
        for (int kk = 0; kk < 16; ++kk) {
            const float4 a0 = *(const float4*)&As[kk * 68 + tp * 8];
            const float4 a1 = *(const float4*)&As[kk * 68 + tp * 8 + 4];
            const float a[8] = {a0.x, a0.y, a0.z, a0.w, a1.x, a1.y, a1.z, a1.w};
            float w[8];
#pragma unroll
            for (int j = 0; j < 8; ++j) w[j] = Ws[kk * 256 + tc + 32 * j];
#pragma unroll
            for (int i = 0; i < 8; ++i)
#pragma unroll
                for (int j = 0; j < 8; ++j)
                    acc[i][j] = fmaf(a[i], w[j], acc[i][j]);
        }
        __syncthreads();
    }

    float bb[8];
#pragma unroll
    for (int j = 0; j < 8; ++j) bb[j] = bo[tc + 32 * j];

#pragma unroll
    for (int i = 0; i < 8; ++i) {
        const int r = row0 + tp * 8 + i;
#pragma unroll
        for (int j = 0; j < 8; ++j)
            out[(size_t)r * 256 + tc + 32 * j] = acc[i][j] + bb[j];
    }
}

// ---------------------------------------------------------------------------
extern "C" void kernel_launch(void* const* d_in, const int* in_sizes, int n_in,
                              void* d_out, int out_size, void* d_ws, size_t ws_size,
                              hipStream_t stream)
{
    const float* query  = (const float*)d_in[0];
    const float* value0 = (const float*)d_in[1];
    const float* value1 = (const float*)d_in[2];
    const float* value2 = (const float*)d_in[3];
    const float* refpts = (const float*)d_in[4];
    const float* Woff   = (const float*)d_in[5];
    const float* boff   = (const float*)d_in[6];
    const float* Wattn  = (const float*)d_in[7];
    const float* battn  = (const float*)d_in[8];
    const float* Wval   = (const float*)d_in[9];
    const float* bval   = (const float*)d_in[10];
    const float* Wout   = (const float*)d_in[11];
    const float* bout   = (const float*)d_in[12];
    float* out = (float*)d_out;

    // workspace: params (46.08 MB) + v bf16 (26.88 MB) = 72.96 MB
    float*          params = (float*)d_ws;
    unsigned short* v0 = (unsigned short*)(params + (size_t)NQ * 288);
    unsigned short* v1 = v0 + (size_t)BATCH * 10000 * 256;
    unsigned short* v2 = v1 + (size_t)BATCH * 2500  * 256;
    float*          outp = out;   // outproj is in-place

    vproj_kernel<<<dim3(207, BATCH), 256, 0, stream>>>(
        value0, value1, value2, Wval, bval, v0, v1, v2);

    qparam_kernel<<<NQ / 64, 256, 0, stream>>>(query, refpts, Woff, boff,
                                               Wattn, battn, params);

    sample_kernel<<<NQ / 4, 256, 0, stream>>>(params, v0, v1, v2, outp);

    outproj_kernel<<<625, 256, 0, stream>>>(outp, Wout, bout, out);
}